// Round 7
// baseline (564.438 us; speedup 1.0000x reference)
//
#include <hip/hip_runtime.h>
#include <math.h>

#define NROWS  16384   // B*S
#define DMODEL 1024
#define NHEAD  16
#define HDIM   64
#define SEQ    4096
#define NBATCH 4
#define NBH    64      // NBATCH*NHEAD
#define SCHUNK 16      // split-K chunks over S for kv aggregation
#define W1     2097152u   // one split weight matrix [1024][2048] in ushorts

typedef __attribute__((ext_vector_type(8))) short bf16x8;
typedef __attribute__((ext_vector_type(4))) float f32x4;

#define VMCNT(N) asm volatile("s_waitcnt vmcnt(" #N ")" ::: "memory")
#define BAR() do { asm volatile("" ::: "memory"); __builtin_amdgcn_s_barrier(); \
                   asm volatile("" ::: "memory"); } while (0)

__device__ __forceinline__ unsigned short f2bf(float f) {
    unsigned u = __float_as_uint(f);
    u += 0x7FFFu + ((u >> 16) & 1u);   // round-to-nearest-even
    return (unsigned short)(u >> 16);
}
__device__ __forceinline__ float bf2f(unsigned short h) {
    return __uint_as_float((unsigned)h << 16);
}

__device__ __forceinline__ void gload16(const void* g, void* l) {
    __builtin_amdgcn_global_load_lds(
        (const __attribute__((address_space(1))) unsigned int*)g,
        (__attribute__((address_space(3))) unsigned int*)l, 16, 0, 0);
}

// ---------------------------------------------------------------------------
// split x [M][1024] f32 -> xs [M][2048] bf16 (cols 0-1023 = hi, 1024-2047 = lo)
// ---------------------------------------------------------------------------
__global__ __launch_bounds__(256)
void split_x(const float* __restrict__ a, unsigned short* __restrict__ dst)
{
    const int idx = blockIdx.x * 256 + threadIdx.x;   // over M*1024/4
    const int row = idx >> 8;
    const int c4  = (idx & 255) * 4;
    const float4 v = ((const float4*)a)[idx];
    ushort4 H, L;
    H.x = f2bf(v.x); L.x = f2bf(v.x - bf2f(H.x));
    H.y = f2bf(v.y); L.y = f2bf(v.y - bf2f(H.y));
    H.z = f2bf(v.z); L.z = f2bf(v.z - bf2f(H.z));
    H.w = f2bf(v.w); L.w = f2bf(v.w - bf2f(H.w));
    *(ushort4*)&dst[(size_t)row * 2048 + c4]        = H;
    *(ushort4*)&dst[(size_t)row * 2048 + 1024 + c4] = L;
}

// all 4 weight matrices -> [y][1024][2048] bf16 hi|lo (y: 0=Wq 1=Wk 2=Wv 3=Wo)
__global__ __launch_bounds__(256)
void split_w4(const float* __restrict__ a0, const float* __restrict__ a1,
              const float* __restrict__ a2, const float* __restrict__ a3,
              unsigned short* __restrict__ dst)
{
    const int y = blockIdx.y;
    const float* src = (y == 0) ? a0 : (y == 1) ? a1 : (y == 2) ? a2 : a3;
    unsigned short* d = dst + (size_t)y * W1;
    const int idx = blockIdx.x * 256 + threadIdx.x;   // over 1024*1024/4
    const int row = idx >> 8;
    const int c4  = (idx & 255) * 4;
    const float4 v = ((const float4*)src)[idx];
    ushort4 H, L;
    H.x = f2bf(v.x); L.x = f2bf(v.x - bf2f(H.x));
    H.y = f2bf(v.y); L.y = f2bf(v.y - bf2f(H.y));
    H.z = f2bf(v.z); L.z = f2bf(v.z - bf2f(H.z));
    H.w = f2bf(v.w); L.w = f2bf(v.w - bf2f(H.w));
    *(ushort4*)&d[(size_t)row * 2048 + c4]        = H;
    *(ushort4*)&d[(size_t)row * 2048 + 1024 + c4] = L;
}

// ---------------------------------------------------------------------------
// Split GEMM as ONE bf16 GEMM, concatenated K=3072: terms [hh | hl | lh].
//   A-col = k<1024 ? k : k-1024   over xs [M][2048] = [xh|xl]
//   B-col = k<2048 ? k : k-2048   over Ws [N][2048] = [Wh|Wl]
// 256x256 tile, BK=64 (48 K-tiles), 8 waves (2Mx4N), per-wave 128x64.
// LDS = 2 buffers x 4 slots of 16KB: [A.k0|A.k1|B.k0|B.k1], slot = 256rowsx32k,
// transposed-cell layout (verified conflict-free in r6). 4 phases per tile:
//   ph0: read B.k0 frags(4)+A.k0 rows0-3(4) | stage A.k0(kt+1) | BAR | 16 MFMA | BAR
//   ph1: read A.k0 rows4-7(4)               | stage B.k0(kt+1) | BAR | 16 MFMA | VMCNT(4) BAR
//   ph2: read B.k1 frags(4)+A.k1 rows0-3(4) | stage A.k1(kt+1) | BAR | 16 MFMA | BAR
//   ph3: read A.k1 rows4-7(4)               | stage B.k1(kt+1) | BAR | 16 MFMA | VMCNT(4) BAR
// Slot stream order == wait order: vmcnt(4) before a barrier guarantees all but
// the last 2 slots landed -- exactly what the next 2 phases read (T3+T4,
// counted wait, never drains in main loop). T5 setprio. T1 XCD swizzle.
// ---------------------------------------------------------------------------
template<int ELU>
__global__ __launch_bounds__(512)
void gemm_8p(const unsigned short* __restrict__ A2, const unsigned short* __restrict__ W2,
             const float* __restrict__ bias, float* __restrict__ C)
{
    __shared__ unsigned short lds[65536];   // 2 x 32768: [Ak0|Ak1|Bk0|Bk1] x 8192
    const int t    = threadIdx.x;
    const int lane = t & 63;
    const int wv   = t >> 6;        // wave 0..7
    const int wr   = wv >> 2;       // M half    0..1  (128 rows)
    const int wcn  = wv & 3;        // N quarter 0..3  (64 cols)

    // XCD swizzle (bijective, 256 blocks): 8 m-panels x 4 n per XCD
    const int bid  = blockIdx.x;
    const int swz  = ((bid & 7) << 5) | (bid >> 3);
    const int am0  = (swz >> 2) * 256;     // A panel row base
    const int bn0  = (swz & 3) * 256;      // W panel row base (= C col base)

    const int fr   = lane & 15;                          // frag row
    const int j0   = lane >> 4;                          // frag k-slot 0..3
    const unsigned fro = (unsigned)((j0 * 16 + fr) * 8); // frag read offset in chunk
    const int srcr = lane & 15;                          // staging source row-in-chunk
    const int srcc = (lane >> 4) * 8;                    // staging source k-offset

    f32x4 acc[8][4];
#pragma unroll
    for (int i = 0; i < 8; ++i)
#pragma unroll
        for (int j = 0; j < 4; ++j)
#pragma unroll
            for (int e = 0; e < 4; ++e) acc[i][j][e] = 0.f;

    // stage slot sl of tile kt: sl 0=A.k0 1=B.k0 2=A.k1 3=B.k1 (2 gload16/thread)
    auto stage_slot = [&](int kt, int sl) {
        const int  kh  = sl >> 1;
        const bool isA = ((sl & 1) == 0);
        const int  k0  = kt * 64 + kh * 32;
        const int  kb  = isA ? ((k0 < 1024) ? k0 : k0 - 1024)
                             : ((k0 < 2048) ? k0 : k0 - 2048);
        const unsigned short* src = isA ? A2 : W2;
        const int  rb  = isA ? am0 : bn0;
        const unsigned slb = ((unsigned)kt & 1u) * 32768u
                           + (isA ? 0u : 16384u) + (unsigned)kh * 8192u;
#pragma unroll
        for (int c = 0; c < 2; ++c) {
            const int ch = wv * 2 + c;    // chunk 0..15 (16 rows x 32 k, transposed cells)
            gload16(src + (size_t)(rb + ch * 16 + srcr) * 2048 + kb + srcc,
                    (unsigned short*)&lds[slb + (unsigned)ch * 512u]);
        }
    };

    bf16x8 bfr[4];   // B frags persist ph0->ph1 and ph2->ph3

    // one phase: ds-reads, optional stage, barrier, 16 MFMA (caller adds end wait+bar)
    auto phase = [&](int kt, int ph, int ktn) {
        const unsigned bb = ((unsigned)kt & 1u) * 32768u;
        const int kh = ph >> 1;
        const int rg = (ph & 1) * 4;     // acc row-group base
        if ((ph & 1) == 0) {
#pragma unroll
            for (int j = 0; j < 4; ++j)
                bfr[j] = *(const bf16x8*)&lds[bb + 16384u + (unsigned)kh * 8192u
                                              + (unsigned)((wcn * 4 + j) * 512) + fro];
        }
        bf16x8 afr[4];
#pragma unroll
        for (int i = 0; i < 4; ++i)
            afr[i] = *(const bf16x8*)&lds[bb + (unsigned)kh * 8192u
                                          + (unsigned)((wr * 8 + rg + i) * 512) + fro];
        if (ktn >= 0) stage_slot(ktn, ph);
        BAR();
        __builtin_amdgcn_s_setprio(1);
#pragma unroll
        for (int i = 0; i < 4; ++i)
#pragma unroll
            for (int j = 0; j < 4; ++j)
                acc[rg + i][j] = __builtin_amdgcn_mfma_f32_16x16x32_bf16(
                    afr[i], bfr[j], acc[rg + i][j], 0, 0, 0);
        __builtin_amdgcn_s_setprio(0);
    };

    // prologue: tile 0's 4 slots in stream order; wait for first 2 slots
    stage_slot(0, 0); stage_slot(0, 1); stage_slot(0, 2); stage_slot(0, 3);
    VMCNT(4);
    BAR();

    for (int kt = 0; kt < 47; ++kt) {
        phase(kt, 0, kt + 1); BAR();
        phase(kt, 1, kt + 1); VMCNT(4); BAR();
        phase(kt, 2, kt + 1); BAR();
        phase(kt, 3, kt + 1); VMCNT(4); BAR();
    }
    // epilogue tile 47 (no staging; drain remaining 2 slots mid-tile)
    phase(47, 0, -1); BAR();
    phase(47, 1, -1); VMCNT(0); BAR();
    phase(47, 2, -1); BAR();
    phase(47, 3, -1);

    // epilogue: C/D layout col=lane&15, row=(lane>>4)*4+reg
    const int crow0 = am0 + wr * 128 + (lane >> 4) * 4;
    const int ccol0 = bn0 + wcn * 64 + fr;
#pragma unroll
    for (int j = 0; j < 4; ++j) {
        const int col = ccol0 + j * 16;
        const float bv = bias[col];
#pragma unroll
        for (int i = 0; i < 8; ++i) {
            const int row = crow0 + i * 16;
#pragma unroll
            for (int r = 0; r < 4; ++r) {
                float v = acc[i][j][r] + bv;
                if (ELU) v = (v > 0.f) ? (v + 1.f) : __expf(v);  // elu(v)+1
                C[(size_t)(row + r) * DMODEL + col] = v;
            }
        }
    }
}

// ---------------------------------------------------------------------------
// kv partials: for (b,h,sc): kvp[d][e] = sum_{s in chunk} k[s,d]*v[s,e],
// ksp[d] = sum k[s,d]. Deterministic split-K, no atomics.
// ---------------------------------------------------------------------------
__global__ __launch_bounds__(512)
void kv_partial(const float* __restrict__ k, const float* __restrict__ v,
                float* __restrict__ kvp, float* __restrict__ ksp)
{
    __shared__ float Ks[32][64];
    __shared__ float Vs[32][64];
    const int t  = threadIdx.x;
    const int bh = blockIdx.x;
    const int b  = bh >> 4;
    const int h  = bh & 15;
    const int sc = blockIdx.y;
    const int d  = t & 63;
    const int e0 = (t >> 6) * 8;

    float acc[8];
#pragma unroll
    for (int j = 0; j < 8; ++j) acc[j] = 0.f;
    float ks = 0.f;

    const size_t rowbase = (size_t)b * SEQ;
    const int sbeg = sc * (SEQ / SCHUNK);       // 256 rows per chunk
    const int send = sbeg + (SEQ / SCHUNK);
    const int lrow = t >> 4;                    // staging: 0..31
    const int lc4  = (t & 15) * 4;

    for (int s0 = sbeg; s0 < send; s0 += 32) {
        const size_t g = (rowbase + s0 + lrow) * DMODEL + h * HDIM + lc4;
        *(float4*)&Ks[lrow][lc4] = *(const float4*)&k[g];
        *(float4*)&Vs[lrow][lc4] = *(const float4*)&v[g];
        __syncthreads();
#pragma unroll 8
        for (int sp = 0; sp < 32; ++sp) {
            const float kd = Ks[sp][d];
            if (t < 64) ks += Ks[sp][t];        // wave 0 only (wave-uniform branch)
            const float4 v0 = *(const float4*)&Vs[sp][e0 + 0];
            const float4 v1 = *(const float4*)&Vs[sp][e0 + 4];
            acc[0] = fmaf(kd, v0.x, acc[0]);  acc[1] = fmaf(kd, v0.y, acc[1]);
            acc[2] = fmaf(kd, v0.z, acc[2]);  acc[3] = fmaf(kd, v0.w, acc[3]);
            acc[4] = fmaf(kd, v1.x, acc[4]);  acc[5] = fmaf(kd, v1.y, acc[5]);
            acc[6] = fmaf(kd, v1.z, acc[6]);  acc[7] = fmaf(kd, v1.w, acc[7]);
        }
        __syncthreads();
    }

    const size_t base = ((size_t)sc * NBH + bh) * HDIM;
    float4 o0; o0.x = acc[0]; o0.y = acc[1]; o0.z = acc[2]; o0.w = acc[3];
    float4 o1; o1.x = acc[4]; o1.y = acc[5]; o1.z = acc[6]; o1.w = acc[7];
    *(float4*)&kvp[(base + d) * HDIM + e0 + 0] = o0;
    *(float4*)&kvp[(base + d) * HDIM + e0 + 4] = o1;
    if (t < 64) ksp[base + t] = ks;
}

__global__ __launch_bounds__(256)
void kv_reduce(const float* __restrict__ kvp, const float* __restrict__ ksp,
               float* __restrict__ kv, float* __restrict__ ksum)
{
    const int i = blockIdx.x * 256 + threadIdx.x;
    const int NKV = NBH * HDIM * HDIM;
    if (i < NKV) {
        float s = 0.f;
#pragma unroll
        for (int c = 0; c < SCHUNK; ++c) s += kvp[(size_t)c * NKV + i];
        kv[i] = s;
    }
    if (i < NBH * HDIM) {
        float s = 0.f;
#pragma unroll
        for (int c = 0; c < SCHUNK; ++c) s += ksp[(size_t)c * NBH * HDIM + i];
        ksum[i] = s;
    }
}

// ---------------------------------------------------------------------------
// att[s,e] = (sum_d q[s,d]*kv[d,e]) / (sum_d q[s,d]*ksum[d] + 1e-6),
// written directly as bf16 hi/lo into the [M][2048] concat layout.
// ---------------------------------------------------------------------------
__global__ __launch_bounds__(256)
void qkv_norm(const float* __restrict__ q, const float* __restrict__ kv,
              const float* __restrict__ ksum, unsigned short* __restrict__ att)
{
    __shared__ float Qs[64][68];
    __shared__ float KVs[64][64];
    __shared__ float kss[64];
    const int t  = threadIdx.x;
    const int s0 = blockIdx.x * 64;
    const int b  = blockIdx.y;
    const int h  = blockIdx.z;
    const int bh = b * NHEAD + h;

#pragma unroll
    for (int i = 0; i < 4; ++i) {
        const int idx = i * 256 + t;
        const int row = idx >> 4;
        const int c4  = (idx & 15) * 4;
        const float4 vq = *(const float4*)&q[((size_t)b * SEQ + s0 + row) * DMODEL + h * HDIM + c4];
        *(float4*)&Qs[row][c4] = vq;
        *(float4*)&((float*)KVs)[idx * 4] = *(const float4*)&kv[(size_t)bh * HDIM * HDIM + idx * 4];
    }
    if (t < 64) kss[t] = ksum[(size_t)bh * HDIM + t];
    __syncthreads();

    const int r  = t >> 2;
    const int e0 = (t & 3) * 16;
    float out[16];
#pragma unroll
    for (int j = 0; j < 16; ++j) out[j] = 0.f;
    float nrm = 0.f;

#pragma unroll 8
    for (int d = 0; d < 64; ++d) {
        const float qd = Qs[r][d];
        nrm = fmaf(qd, kss[d], nrm);
        const float4 k0 = *(const float4*)&KVs[d][e0 + 0];
        const float4 k1 = *(const float4*)&KVs[d][e0 + 4];
        const float4 k2 = *(const float4*)&KVs[d][e0 + 8];
        const float4 k3 = *(const float4*)&KVs[d][e0 + 12];
        out[0]  = fmaf(qd, k0.x, out[0]);  out[1]  = fmaf(qd, k0.y, out[1]);
        out[2]  = fmaf(qd, k0.z, out[2]);  out[3]  = fmaf(qd, k0.w, out[3]);
        out[4]  = fmaf(qd, k1.x, out[4]);  out[5]  = fmaf(qd, k1.y, out[5]);
        out[6]  = fmaf(qd, k1.z, out[6]);  out[7]  = fmaf(qd, k1.w, out[7]);
        out[8]  = fmaf(qd, k2.x, out[8]);  out[9]  = fmaf(qd, k2.y, out[9]);
        out[10] = fmaf(qd, k2.z, out[10]); out[11] = fmaf(qd, k2.w, out[11]);
        out[12] = fmaf(qd, k3.x, out[12]); out[13] = fmaf(qd, k3.y, out[13]);
        out[14] = fmaf(qd, k3.z, out[14]); out[15] = fmaf(qd, k3.w, out[15]);
    }

    const float inv = 1.f / (nrm + 1e-6f);
    const size_t gb = ((size_t)b * SEQ + s0 + r) * 2048 + h * HDIM + e0;
#pragma unroll
    for (int g4 = 0; g4 < 4; ++g4) {
        ushort4 H, L;
        const float v0 = out[g4*4+0] * inv;
        const float v1 = out[g4*4+1] * inv;
        const float v2 = out[g4*4+2] * inv;
        const float v3 = out[g4*4+3] * inv;
        H.x = f2bf(v0); L.x = f2bf(v0 - bf2f(H.x));
        H.y = f2bf(v1); L.y = f2bf(v1 - bf2f(H.y));
        H.z = f2bf(v2); L.z = f2bf(v2 - bf2f(H.z));
        H.w = f2bf(v3); L.w = f2bf(v3 - bf2f(H.w));
        *(ushort4*)&att[gb + g4 * 4]        = H;
        *(ushort4*)&att[gb + 1024 + g4 * 4] = L;
    }
}

// ---------------------------------------------------------------------------
extern "C" void kernel_launch(void* const* d_in, const int* in_sizes, int n_in,
                              void* d_out, int out_size, void* d_ws, size_t ws_size,
                              hipStream_t stream)
{
    const float* x  = (const float*)d_in[0];
    const float* Wq = (const float*)d_in[1];
    const float* bq = (const float*)d_in[2];
    const float* Wk = (const float*)d_in[3];
    const float* bk = (const float*)d_in[4];
    const float* Wv = (const float*)d_in[5];
    const float* bv = (const float*)d_in[6];
    const float* Wo = (const float*)d_in[7];
    const float* bo = (const float*)d_in[8];

    // workspace layout (~153 MB):
    unsigned short* xs  = (unsigned short*)d_ws;                   // [16384][2048] = [xh|xl], later att
    unsigned short* wsp = xs + (size_t)NROWS * 2048;               // 4 x [1024][2048] = [Wh|Wl] per matrix
    float* buf0 = (float*)(wsp + 4u * W1);                         // k, then q (fp32)
    float* kv   = buf0 + (size_t)NROWS * DMODEL;                   // [NBH][64][64]
    float* ksum = kv + NBH * HDIM * HDIM;                          // [NBH][64]
    float* kvp  = ksum + NBH * HDIM;                               // [SCHUNK][NBH][64][64]
    float* ksp  = kvp + (size_t)SCHUNK * NBH * HDIM * HDIM;        // [SCHUNK][NBH][64]
    float* vbuf = (float*)d_out;                                   // v lives in d_out (dead before final GEMM)

    const dim3 gg(256);   // (16384/256) x (1024/256) = 64 x 4, flat + XCD swizzle

    // convert weights + x to bf16 hi/lo concat layouts
    split_w4<<<dim3(1024, 4), 256, 0, stream>>>(Wq, Wk, Wv, Wo, wsp);
    split_x<<<16384, 256, 0, stream>>>(x, xs);
    // k = elu(x@Wk^T + bk)+1 ; v = x@Wv^T + bv
    gemm_8p<1><<<gg, 512, 0, stream>>>(xs, wsp + 1u * W1, bk, buf0);
    gemm_8p<0><<<gg, 512, 0, stream>>>(xs, wsp + 2u * W1, bv, vbuf);
    // kv, ksum (deterministic split-K + reduce)
    kv_partial<<<dim3(NBH, SCHUNK), 512, 0, stream>>>(buf0, vbuf, kvp, ksp);
    kv_reduce<<<1024, 256, 0, stream>>>(kvp, ksp, kv, ksum);
    // q = elu(x@Wq^T + bq)+1   (overwrites k)
    gemm_8p<1><<<gg, 512, 0, stream>>>(xs, wsp, bq, buf0);
    // att = (q@kv)/(q@ksum + 1e-6), fused hi/lo split into xs (x is dead)
    qkv_norm<<<dim3(SEQ / 64, NBATCH, NHEAD), 256, 0, stream>>>(buf0, kv, ksum, xs);
    // out = att@Wo^T + bo  (overwrites v in d_out)
    gemm_8p<0><<<gg, 512, 0, stream>>>(xs, wsp + 3u * W1, bo, (float*)d_out);
}

// Round 8
// 488.174 us; speedup vs baseline: 1.1562x; 1.1562x over previous
//
#include <hip/hip_runtime.h>
#include <math.h>

#define NROWS  16384   // B*S
#define DMODEL 1024
#define NHEAD  16
#define HDIM   64
#define SEQ    4096
#define NBATCH 4
#define NBH    64      // NBATCH*NHEAD
#define SCHUNK 16      // split-K chunks over S for kv aggregation
#define M1     1048576u

typedef __attribute__((ext_vector_type(8))) short bf16x8;
typedef __attribute__((ext_vector_type(4))) float f32x4;

__device__ __forceinline__ unsigned short f2bf(float f) {
    unsigned u = __float_as_uint(f);
    u += 0x7FFFu + ((u >> 16) & 1u);   // round-to-nearest-even
    return (unsigned short)(u >> 16);
}
__device__ __forceinline__ float bf2f(unsigned short h) {
    return __uint_as_float((unsigned)h << 16);
}

__device__ __forceinline__ void gload16(const void* g, void* l) {
    __builtin_amdgcn_global_load_lds(
        (const __attribute__((address_space(1))) unsigned int*)g,
        (__attribute__((address_space(3))) unsigned int*)l, 16, 0, 0);
}

// ---------------------------------------------------------------------------
// split fp32 -> bf16 hi/lo pair (grid-stride, float4/ushort4 vectorized)
// ---------------------------------------------------------------------------
__global__ __launch_bounds__(256)
void split_pair(const float* __restrict__ a, unsigned short* __restrict__ hi,
                unsigned short* __restrict__ lo, int n4)
{
    int i = blockIdx.x * 256 + threadIdx.x;
    const int stride = gridDim.x * 256;
    for (; i < n4; i += stride) {
        const float4 v = ((const float4*)a)[i];
        ushort4 H, L;
        H.x = f2bf(v.x); L.x = f2bf(v.x - bf2f(H.x));
        H.y = f2bf(v.y); L.y = f2bf(v.y - bf2f(H.y));
        H.z = f2bf(v.z); L.z = f2bf(v.z - bf2f(H.z));
        H.w = f2bf(v.w); L.w = f2bf(v.w - bf2f(H.w));
        ((ushort4*)hi)[i] = H;
        ((ushort4*)lo)[i] = L;
    }
}

// all 4 weight matrices in one launch: dst = [Wq_h,Wq_l,Wk_h,Wk_l,Wv_h,Wv_l,Wo_h,Wo_l]
__global__ __launch_bounds__(256)
void split_w4(const float* __restrict__ a0, const float* __restrict__ a1,
              const float* __restrict__ a2, const float* __restrict__ a3,
              unsigned short* __restrict__ dst)
{
    const int y = blockIdx.y;
    const float* src = (y == 0) ? a0 : (y == 1) ? a1 : (y == 2) ? a2 : a3;
    unsigned short* hi = dst + (size_t)y * 2u * M1;
    unsigned short* lo = hi + M1;
    const int i = blockIdx.x * 256 + threadIdx.x;   // 0..262143 (= 1M/4)
    const float4 v = ((const float4*)src)[i];
    ushort4 H, L;
    H.x = f2bf(v.x); L.x = f2bf(v.x - bf2f(H.x));
    H.y = f2bf(v.y); L.y = f2bf(v.y - bf2f(H.y));
    H.z = f2bf(v.z); L.z = f2bf(v.z - bf2f(H.z));
    H.w = f2bf(v.w); L.w = f2bf(v.w - bf2f(H.w));
    ((ushort4*)hi)[i] = H;
    ((ushort4*)lo)[i] = L;
}

// ---------------------------------------------------------------------------
// Split-bf16 GEMM (NT), round-4 schedule + transposed-cell LDS layout.
// C = A@W^T + bias, optional elu+1. 256x256 tile, BK=32, 8 waves (2Mx4N),
// per-wave 128x64, 3 MFMA passes (hh+hl+lh). LDS 2 x {Ah,Al,Bh,Bl}[256][32]
// = 128 KiB dbuf. 4 phases/K-step, raw barriers, setprio on MFMA, prefetch
// one region per phase (stays in flight across barriers), single
// __syncthreads() per K-step at buffer handoff.  NEW vs r4: each 16-row x 32-k
// chunk is stored as transposed cells [kslot][row] via the per-lane GLOBAL
// source permutation (LDS dest stays linear per gload_lds rules); frag reads
// become 256B-contiguous -> bank-conflict-free (r6/r7-verified: 0 conflicts).
// ---------------------------------------------------------------------------
template<int ELU>
__global__ __launch_bounds__(512)
void gemm_split8(const unsigned short* __restrict__ Ah, const unsigned short* __restrict__ Al,
                 const unsigned short* __restrict__ Wh, const unsigned short* __restrict__ Wl,
                 const float* __restrict__ bias, float* __restrict__ C)
{
    __shared__ unsigned short lds[2 * 32768];   // 2 x 64 KiB buffers
    const int t    = threadIdx.x;
    const int lane = t & 63;
    const int wv   = t >> 6;        // wave 0..7
    const int wr   = wv >> 2;       // M half   0..1
    const int wcn  = wv & 3;        // N quarter 0..3

    // XCD swizzle (bijective, 256 blocks): 8 m-panels x 4 n per XCD
    const int bid  = blockIdx.x;
    const int swz  = ((bid & 7) << 5) | (bid >> 3);
    const int am0  = (swz >> 2) * 256;     // A panel row base
    const int bn0  = (swz & 3) * 256;      // W panel row base (= C col base)

    const int fr   = lane & 15;            // frag row
    const int j0   = lane >> 4;            // frag k-slot 0..3
    const unsigned fro = (unsigned)((j0 * 16 + fr) * 8);  // within-chunk frag offset
    const int srcr = lane & 15;            // staging source: row within chunk
    const int srcc = (lane >> 4) * 8;      // staging source: k offset (8 bf16 = 16B)

    f32x4 acc[8][4];
#pragma unroll
    for (int i = 0; i < 8; ++i)
#pragma unroll
        for (int j = 0; j < 4; ++j)
#pragma unroll
            for (int e = 0; e < 4; ++e) acc[i][j][e] = 0.f;

    // stage one region (ph: 0=Ah 1=Al 2=Bh 3=Bl) for k0 into buffer wb.
    // chunk = 16 rows x 32 k, stored transposed-cell; dest linear in lane.
    auto stage = [&](int ph, int k0, unsigned wb) {
        const unsigned short* gs = (ph == 0) ? Ah : (ph == 1) ? Al : (ph == 2) ? Wh : Wl;
        const int rbase = (ph < 2) ? am0 : bn0;
#pragma unroll
        for (int c = 0; c < 2; ++c) {
            const int grow = rbase + c * 128 + wv * 16 + srcr;
            gload16(gs + (size_t)grow * DMODEL + k0 + srcc,
                    (unsigned short*)&lds[wb + (unsigned)ph * 8192u + (unsigned)(c * 8 + wv) * 512u]);
        }
    };

    // prologue: stage K-step 0 into buffer 0
#pragma unroll
    for (int ph = 0; ph < 4; ++ph) stage(ph, 0, 0u);
    __syncthreads();

    for (int ks = 0; ks < 32; ++ks) {
        const unsigned rb = (ks & 1) ? 32768u : 0u;
        const unsigned wb = rb ^ 32768u;
        const int k0n = (ks + 1) * 32;
        const bool pf = (ks < 31);

        bf16x8 bh[4], bl[4];
#pragma unroll
        for (int ph = 0; ph < 4; ++ph) {
            if (ph == 0) {
#pragma unroll
                for (int j = 0; j < 4; ++j) {
                    const unsigned ch = (unsigned)(wcn * 4 + j) * 512u;   // B chunk
                    bh[j] = *(const bf16x8*)&lds[rb + 16384u + ch + fro];
                    bl[j] = *(const bf16x8*)&lds[rb + 24576u + ch + fro];
                }
            }
            bf16x8 a_h[2], a_l[2];
#pragma unroll
            for (int i2 = 0; i2 < 2; ++i2) {
                const unsigned ch = (unsigned)(wr * 8 + ph * 2 + i2) * 512u;  // A chunk
                a_h[i2] = *(const bf16x8*)&lds[rb + ch + fro];
                a_l[i2] = *(const bf16x8*)&lds[rb + 8192u + ch + fro];
            }
            if (pf) stage(ph, k0n, wb);        // prefetch: stays in flight across barriers
            __builtin_amdgcn_s_barrier();
            __builtin_amdgcn_s_setprio(1);
#pragma unroll
            for (int i2 = 0; i2 < 2; ++i2)
#pragma unroll
                for (int j = 0; j < 4; ++j) {
                    acc[ph * 2 + i2][j] = __builtin_amdgcn_mfma_f32_16x16x32_bf16(a_h[i2], bh[j], acc[ph * 2 + i2][j], 0, 0, 0);
                    acc[ph * 2 + i2][j] = __builtin_amdgcn_mfma_f32_16x16x32_bf16(a_h[i2], bl[j], acc[ph * 2 + i2][j], 0, 0, 0);
                    acc[ph * 2 + i2][j] = __builtin_amdgcn_mfma_f32_16x16x32_bf16(a_l[i2], bh[j], acc[ph * 2 + i2][j], 0, 0, 0);
                }
            __builtin_amdgcn_s_setprio(0);
            if (ph < 3) __builtin_amdgcn_s_barrier();
        }
        __syncthreads();   // vmcnt(0)+barrier: buffer handoff (once per K-step)
    }

    // epilogue: C/D layout col=lane&15, row=(lane>>4)*4+reg
    const int crow0 = am0 + wr * 128 + (lane >> 4) * 4;
    const int ccol0 = bn0 + wcn * 64 + fr;
#pragma unroll
    for (int j = 0; j < 4; ++j) {
        const int col = ccol0 + j * 16;
        const float bv = bias[col];
#pragma unroll
        for (int i = 0; i < 8; ++i) {
            const int row = crow0 + i * 16;
#pragma unroll
            for (int r = 0; r < 4; ++r) {
                float v = acc[i][j][r] + bv;
                if (ELU) v = (v > 0.f) ? (v + 1.f) : __expf(v);  // elu(v)+1
                C[(size_t)(row + r) * DMODEL + col] = v;
            }
        }
    }
}

// ---------------------------------------------------------------------------
// kv partials: for (b,h,sc): kvp[d][e] = sum_{s in chunk} k[s,d]*v[s,e],
// ksp[d] = sum k[s,d]. Deterministic split-K, no atomics.
// ---------------------------------------------------------------------------
__global__ __launch_bounds__(512)
void kv_partial(const float* __restrict__ k, const float* __restrict__ v,
                float* __restrict__ kvp, float* __restrict__ ksp)
{
    __shared__ float Ks[32][64];
    __shared__ float Vs[32][64];
    const int t  = threadIdx.x;
    const int bh = blockIdx.x;
    const int b  = bh >> 4;
    const int h  = bh & 15;
    const int sc = blockIdx.y;
    const int d  = t & 63;
    const int e0 = (t >> 6) * 8;

    float acc[8];
#pragma unroll
    for (int j = 0; j < 8; ++j) acc[j] = 0.f;
    float ks = 0.f;

    const size_t rowbase = (size_t)b * SEQ;
    const int sbeg = sc * (SEQ / SCHUNK);       // 256 rows per chunk
    const int send = sbeg + (SEQ / SCHUNK);
    const int lrow = t >> 4;                    // staging: 0..31
    const int lc4  = (t & 15) * 4;

    for (int s0 = sbeg; s0 < send; s0 += 32) {
        const size_t g = (rowbase + s0 + lrow) * DMODEL + h * HDIM + lc4;
        *(float4*)&Ks[lrow][lc4] = *(const float4*)&k[g];
        *(float4*)&Vs[lrow][lc4] = *(const float4*)&v[g];
        __syncthreads();
#pragma unroll 8
        for (int sp = 0; sp < 32; ++sp) {
            const float kd = Ks[sp][d];
            if (t < 64) ks += Ks[sp][t];        // wave 0 only (wave-uniform branch)
            const float4 v0 = *(const float4*)&Vs[sp][e0 + 0];
            const float4 v1 = *(const float4*)&Vs[sp][e0 + 4];
            acc[0] = fmaf(kd, v0.x, acc[0]);  acc[1] = fmaf(kd, v0.y, acc[1]);
            acc[2] = fmaf(kd, v0.z, acc[2]);  acc[3] = fmaf(kd, v0.w, acc[3]);
            acc[4] = fmaf(kd, v1.x, acc[4]);  acc[5] = fmaf(kd, v1.y, acc[5]);
            acc[6] = fmaf(kd, v1.z, acc[6]);  acc[7] = fmaf(kd, v1.w, acc[7]);
        }
        __syncthreads();
    }

    const size_t base = ((size_t)sc * NBH + bh) * HDIM;
    float4 o0; o0.x = acc[0]; o0.y = acc[1]; o0.z = acc[2]; o0.w = acc[3];
    float4 o1; o1.x = acc[4]; o1.y = acc[5]; o1.z = acc[6]; o1.w = acc[7];
    *(float4*)&kvp[(base + d) * HDIM + e0 + 0] = o0;
    *(float4*)&kvp[(base + d) * HDIM + e0 + 4] = o1;
    if (t < 64) ksp[base + t] = ks;
}

__global__ __launch_bounds__(256)
void kv_reduce(const float* __restrict__ kvp, const float* __restrict__ ksp,
               float* __restrict__ kv, float* __restrict__ ksum)
{
    const int i = blockIdx.x * 256 + threadIdx.x;
    const int NKV = NBH * HDIM * HDIM;
    if (i < NKV) {
        float s = 0.f;
#pragma unroll
        for (int c = 0; c < SCHUNK; ++c) s += kvp[(size_t)c * NKV + i];
        kv[i] = s;
    }
    if (i < NBH * HDIM) {
        float s = 0.f;
#pragma unroll
        for (int c = 0; c < SCHUNK; ++c) s += ksp[(size_t)c * NBH * HDIM + i];
        ksum[i] = s;
    }
}

// ---------------------------------------------------------------------------
// att[s,e] = (sum_d q[s,d]*kv[d,e]) / (sum_d q[s,d]*ksum[d] + 1e-6),
// written directly as bf16 hi/lo (fused split for the final GEMM's A-operand).
// ---------------------------------------------------------------------------
__global__ __launch_bounds__(256)
void qkv_norm(const float* __restrict__ q, const float* __restrict__ kv,
              const float* __restrict__ ksum,
              unsigned short* __restrict__ ah, unsigned short* __restrict__ al)
{
    __shared__ float Qs[64][68];
    __shared__ float KVs[64][64];
    __shared__ float kss[64];
    const int t  = threadIdx.x;
    const int s0 = blockIdx.x * 64;
    const int b  = blockIdx.y;
    const int h  = blockIdx.z;
    const int bh = b * NHEAD + h;

#pragma unroll
    for (int i = 0; i < 4; ++i) {
        const int idx = i * 256 + t;
        const int row = idx >> 4;
        const int c4  = (idx & 15) * 4;
        const float4 vq = *(const float4*)&q[((size_t)b * SEQ + s0 + row) * DMODEL + h * HDIM + c4];
        *(float4*)&Qs[row][c4] = vq;
        *(float4*)&((float*)KVs)[idx * 4] = *(const float4*)&kv[(size_t)bh * HDIM * HDIM + idx * 4];
    }
    if (t < 64) kss[t] = ksum[(size_t)bh * HDIM + t];
    __syncthreads();

    const int r  = t >> 2;
    const int e0 = (t & 3) * 16;
    float out[16];
#pragma unroll
    for (int j = 0; j < 16; ++j) out[j] = 0.f;
    float nrm = 0.f;

#pragma unroll 8
    for (int d = 0; d < 64; ++d) {
        const float qd = Qs[r][d];
        nrm = fmaf(qd, kss[d], nrm);
        const float4 k0 = *(const float4*)&KVs[d][e0 + 0];
        const float4 k1 = *(const float4*)&KVs[d][e0 + 4];
        const float4 k2 = *(const float4*)&KVs[d][e0 + 8];
        const float4 k3 = *(const float4*)&KVs[d][e0 + 12];
        out[0]  = fmaf(qd, k0.x, out[0]);  out[1]  = fmaf(qd, k0.y, out[1]);
        out[2]  = fmaf(qd, k0.z, out[2]);  out[3]  = fmaf(qd, k0.w, out[3]);
        out[4]  = fmaf(qd, k1.x, out[4]);  out[5]  = fmaf(qd, k1.y, out[5]);
        out[6]  = fmaf(qd, k1.z, out[6]);  out[7]  = fmaf(qd, k1.w, out[7]);
        out[8]  = fmaf(qd, k2.x, out[8]);  out[9]  = fmaf(qd, k2.y, out[9]);
        out[10] = fmaf(qd, k2.z, out[10]); out[11] = fmaf(qd, k2.w, out[11]);
        out[12] = fmaf(qd, k3.x, out[12]); out[13] = fmaf(qd, k3.y, out[13]);
        out[14] = fmaf(qd, k3.z, out[14]); out[15] = fmaf(qd, k3.w, out[15]);
    }

    const float inv = 1.f / (nrm + 1e-6f);
    const size_t gbase = ((size_t)b * SEQ + s0 + r) * DMODEL + h * HDIM + e0;
#pragma unroll
    for (int g4 = 0; g4 < 4; ++g4) {
        ushort4 H, L;
        const float v0 = out[g4*4+0] * inv;
        const float v1 = out[g4*4+1] * inv;
        const float v2 = out[g4*4+2] * inv;
        const float v3 = out[g4*4+3] * inv;
        H.x = f2bf(v0); L.x = f2bf(v0 - bf2f(H.x));
        H.y = f2bf(v1); L.y = f2bf(v1 - bf2f(H.y));
        H.z = f2bf(v2); L.z = f2bf(v2 - bf2f(H.z));
        H.w = f2bf(v3); L.w = f2bf(v3 - bf2f(H.w));
        *(ushort4*)&ah[gbase + g4 * 4] = H;
        *(ushort4*)&al[gbase + g4 * 4] = L;
    }
}

// ---------------------------------------------------------------------------
extern "C" void kernel_launch(void* const* d_in, const int* in_sizes, int n_in,
                              void* d_out, int out_size, void* d_ws, size_t ws_size,
                              hipStream_t stream)
{
    const float* x  = (const float*)d_in[0];
    const float* Wq = (const float*)d_in[1];
    const float* bq = (const float*)d_in[2];
    const float* Wk = (const float*)d_in[3];
    const float* bk = (const float*)d_in[4];
    const float* Wv = (const float*)d_in[5];
    const float* bv = (const float*)d_in[6];
    const float* Wo = (const float*)d_in[7];
    const float* bo = (const float*)d_in[8];

    // workspace layout (~163 MB):
    unsigned short* xh = (unsigned short*)d_ws;                    // [16384][1024] bf16 hi (x, then att)
    unsigned short* xl = xh + (size_t)NROWS * DMODEL;              // lo
    unsigned short* wsp = xl + (size_t)NROWS * DMODEL;             // 8 x 1M bf16: q_h,q_l,k_h,k_l,v_h,v_l,o_h,o_l
    float* buf0 = (float*)(wsp + 8u * M1);                         // k, then q (fp32)
    float* kv   = buf0 + (size_t)NROWS * DMODEL;                   // [NBH][64][64]
    float* ksum = kv + NBH * HDIM * HDIM;                          // [NBH][64]
    float* kvp  = ksum + NBH * HDIM;                               // [SCHUNK][NBH][64][64]
    float* ksp  = kvp + (size_t)SCHUNK * NBH * HDIM * HDIM;        // [SCHUNK][NBH][64]
    float* vbuf = (float*)d_out;                                   // v lives in d_out (dead before final GEMM)

    const dim3 gg(256);   // (16384/256) x (1024/256) = 64 x 4, flat + XCD swizzle
    const int n4x = NROWS * DMODEL / 4;

    // convert weights + x to bf16 hi/lo
    split_w4<<<dim3(1024, 4), 256, 0, stream>>>(Wq, Wk, Wv, Wo, wsp);
    split_pair<<<4096, 256, 0, stream>>>(x, xh, xl, n4x);
    // k = elu(x@Wk^T + bk)+1 ; v = x@Wv^T + bv
    gemm_split8<1><<<gg, 512, 0, stream>>>(xh, xl, wsp + 2u * M1, wsp + 3u * M1, bk, buf0);
    gemm_split8<0><<<gg, 512, 0, stream>>>(xh, xl, wsp + 4u * M1, wsp + 5u * M1, bv, vbuf);
    // kv, ksum (deterministic split-K + reduce)
    kv_partial<<<dim3(NBH, SCHUNK), 512, 0, stream>>>(buf0, vbuf, kvp, ksp);
    kv_reduce<<<1024, 256, 0, stream>>>(kvp, ksp, kv, ksum);
    // q = elu(x@Wq^T + bq)+1   (overwrites k)
    gemm_split8<1><<<gg, 512, 0, stream>>>(xh, xl, wsp, wsp + M1, bq, buf0);
    // att = (q@kv)/(q@ksum + 1e-6), fused bf16 hi/lo split (x split is dead; reuse xh/xl)
    qkv_norm<<<dim3(SEQ / 64, NBATCH, NHEAD), 256, 0, stream>>>(buf0, kv, ksum, xh, xl);
    // out = att@Wo^T + bo  (overwrites v in d_out)
    gemm_split8<0><<<gg, 512, 0, stream>>>(xh, xl, wsp + 6u * M1, wsp + 7u * M1, bo, (float*)d_out);
}